// Round 1
// baseline (46908.011 us; speedup 1.0000x reference)
//
#include <hip/hip_runtime.h>
#include <math.h>

// GRNNTransformGated — fp32 baseline.
// Structure: 16 levels over a binary-DAG "tree"; level 15 is leaf-embed only,
// levels 14..0 run the fused gated step. Levels are sequentially dependent ->
// one kernel launch per level. Per-node work is fully independent within a
// level (softmax is over the 64 hidden units per gate, i.e. row-local).
//
// h ping-pong: buf(k) = (k even) ? d_out : d_ws  -> level 0 lands in d_out.
// Requires ws_size >= 65536*64*4 = 16 MiB.

#define N_NODES 65536
#define FEAT 7
#define H 64
#define NT 16           // nodes per block
#define BLOCK 256
#define HP 196          // padded stride for 192-wide LDS tiles (196*4B, 16B-aligned rows, bank-stagger 4)
#define HHP 68          // padded stride for 64-wide tile
#define ZP 260          // padded stride for 256-wide tile

__global__ __launch_bounds__(BLOCK) void grnn_leaf_kernel(
    const float* __restrict__ contents, const float* __restrict__ Wu,
    const float* __restrict__ bu, float* __restrict__ h_out)
{
    int t = blockIdx.x * BLOCK + threadIdx.x;   // one thread per (node, j)
    int node = t >> 6;
    int j = t & 63;
    const float* c = contents + (size_t)15 * N_NODES * FEAT + (size_t)node * FEAT;
    float acc = bu[j];
#pragma unroll
    for (int f = 0; f < FEAT; ++f) acc += c[f] * Wu[j * FEAT + f];
    h_out[t] = fmaxf(acc, 0.f);
}

__global__ __launch_bounds__(BLOCK) void grnn_step_kernel(
    const float* __restrict__ contents_k,   // this level's contents base
    const int*   __restrict__ children_k,   // this level's children base
    const float* __restrict__ h_in,         // deeper level's h (gather source)
    const float* __restrict__ Wu, const float* __restrict__ bu,
    const float* __restrict__ Wr, const float* __restrict__ br,
    const float* __restrict__ Wh, const float* __restrict__ bh,
    const float* __restrict__ Wz, const float* __restrict__ bz,
    float* __restrict__ h_out)
{
    __shared__ __align__(16) float hhu[NT][HP];   // [h_L(64) | h_R(64) | u_k(64)]
    __shared__ __align__(16) float rh [NT][HP];   // sigmoid(r) * hhu
    __shared__ __align__(16) float hH [NT][HHP];  // relu((r*hhu)@Wh.T + bh)
    __shared__ __align__(16) float zt [NT][ZP];   // z logits -> exp(z - max)
    __shared__ float rden[NT][4];                 // 1/sum per (node, gate)

    const int tid = threadIdx.x;
    const int node0 = blockIdx.x * NT;
    const int n   = tid >> 4;    // 0..15 : node within tile (16 lanes share n -> LDS broadcast)
    const int c16 = tid & 15;    // output-column group

    // ---- u_k = relu(contents @ Wu.T + bu) -> hhu[:,128:192]
    {
        const float* cptr = contents_k + (size_t)(node0 + n) * FEAT;
        float cf[FEAT];
#pragma unroll
        for (int f = 0; f < FEAT; ++f) cf[f] = cptr[f];
#pragma unroll
        for (int jj = 0; jj < 4; ++jj) {
            int j = c16 + 16 * jj;
            float acc = bu[j];
#pragma unroll
            for (int f = 0; f < FEAT; ++f) acc += cf[f] * Wu[j * FEAT + f];
            hhu[n][128 + j] = fmaxf(acc, 0.f);
        }
    }
    // ---- gather h_L, h_R rows (coalesced: 64 consecutive lanes read 64 consecutive floats)
    {
#pragma unroll
        for (int it = 0; it < 8; ++it) {
            int t = tid + it * BLOCK;        // 0..2047
            int nn   = t >> 7;               // node within tile
            int side = (t >> 6) & 1;         // 0 = L, 1 = R
            int j    = t & 63;
            int child = children_k[(size_t)(node0 + nn) * 2 + side];
            hhu[nn][side * 64 + j] = h_in[(size_t)child * H + j];
        }
    }
    __syncthreads();

    // ---- r = sigmoid(hhu @ Wr.T + br);  rh = r * hhu
    {
        float acc[12];
#pragma unroll
        for (int ii = 0; ii < 12; ++ii) acc[ii] = br[c16 + 16 * ii];
        for (int k = 0; k < 192; k += 4) {
            float4 hv = *(const float4*)&hhu[n][k];
#pragma unroll
            for (int ii = 0; ii < 12; ++ii) {
                int i = c16 + 16 * ii;
                float4 w = *(const float4*)&Wr[(size_t)i * 192 + k];
                acc[ii] += hv.x * w.x + hv.y * w.y + hv.z * w.z + hv.w * w.w;
            }
        }
#pragma unroll
        for (int ii = 0; ii < 12; ++ii) {
            int i = c16 + 16 * ii;
            float rv = 1.f / (1.f + __expf(-acc[ii]));
            rh[n][i] = rv * hhu[n][i];
        }
    }
    __syncthreads();

    // ---- h_H = relu(rh @ Wh.T + bh)
    {
        float acc[4];
#pragma unroll
        for (int ii = 0; ii < 4; ++ii) acc[ii] = bh[c16 + 16 * ii];
        for (int k = 0; k < 192; k += 4) {
            float4 hv = *(const float4*)&rh[n][k];
#pragma unroll
            for (int ii = 0; ii < 4; ++ii) {
                int i = c16 + 16 * ii;
                float4 w = *(const float4*)&Wh[(size_t)i * 192 + k];
                acc[ii] += hv.x * w.x + hv.y * w.y + hv.z * w.z + hv.w * w.w;
            }
        }
#pragma unroll
        for (int ii = 0; ii < 4; ++ii)
            hH[n][c16 + 16 * ii] = fmaxf(acc[ii], 0.f);
    }
    __syncthreads();

    // ---- z = concat([h_H, hhu]) @ Wz.T + bz
    {
        float acc[16];
#pragma unroll
        for (int ii = 0; ii < 16; ++ii) acc[ii] = bz[c16 + 16 * ii];
        for (int k = 0; k < 64; k += 4) {          // first 64 inputs: h_H
            float4 hv = *(const float4*)&hH[n][k];
#pragma unroll
            for (int ii = 0; ii < 16; ++ii) {
                int i = c16 + 16 * ii;
                float4 w = *(const float4*)&Wz[(size_t)i * 256 + k];
                acc[ii] += hv.x * w.x + hv.y * w.y + hv.z * w.z + hv.w * w.w;
            }
        }
        for (int k = 0; k < 192; k += 4) {         // remaining 192 inputs: hhu
            float4 hv = *(const float4*)&hhu[n][k];
#pragma unroll
            for (int ii = 0; ii < 16; ++ii) {
                int i = c16 + 16 * ii;
                float4 w = *(const float4*)&Wz[(size_t)i * 256 + 64 + k];
                acc[ii] += hv.x * w.x + hv.y * w.y + hv.z * w.z + hv.w * w.w;
            }
        }
#pragma unroll
        for (int ii = 0; ii < 16; ++ii) zt[n][c16 + 16 * ii] = acc[ii];
    }
    __syncthreads();

    // ---- per-(node, gate) softmax over the 64 hidden units
    // 64 tasks, 4 threads each: lanes differing in tid bits 0..1 share a task.
    {
        int sn = tid >> 4;            // node
        int g  = (tid >> 2) & 3;      // gate
        int q  = tid & 3;             // quarter of the 64 js
        float m = -INFINITY;
#pragma unroll
        for (int jj = 0; jj < 16; ++jj)
            m = fmaxf(m, zt[sn][g * 64 + q * 16 + jj]);
        m = fmaxf(m, __shfl_xor(m, 1));
        m = fmaxf(m, __shfl_xor(m, 2));
        float s = 0.f;
#pragma unroll
        for (int jj = 0; jj < 16; ++jj) {
            int idx = g * 64 + q * 16 + jj;
            float e = __expf(zt[sn][idx] - m);
            zt[sn][idx] = e;
            s += e;
        }
        s += __shfl_xor(s, 1);
        s += __shfl_xor(s, 2);
        if (q == 0) rden[sn][g] = 1.f / s;
    }
    __syncthreads();

    // ---- h_new = z0*h_H + z1*h_L + z2*h_R + z3*u_k
    {
        size_t node = node0 + n;
#pragma unroll
        for (int jj = 0; jj < 4; ++jj) {
            int j = c16 + 16 * jj;
            float v = zt[n][j]       * rden[n][0] * hH[n][j]
                    + zt[n][64 + j]  * rden[n][1] * hhu[n][j]
                    + zt[n][128 + j] * rden[n][2] * hhu[n][64 + j]
                    + zt[n][192 + j] * rden[n][3] * hhu[n][128 + j];
            h_out[node * H + j] = v;
        }
    }
}

extern "C" void kernel_launch(void* const* d_in, const int* in_sizes, int n_in,
                              void* d_out, int out_size, void* d_ws, size_t ws_size,
                              hipStream_t stream) {
    const float* contents = (const float*)d_in[0];
    const int*   children = (const int*)d_in[1];
    const float* Wu = (const float*)d_in[2];
    const float* bu = (const float*)d_in[3];
    const float* Wr = (const float*)d_in[4];
    const float* br = (const float*)d_in[5];
    const float* Wh = (const float*)d_in[6];
    const float* bh = (const float*)d_in[7];
    const float* Wz = (const float*)d_in[8];
    const float* bz = (const float*)d_in[9];
    float* out = (float*)d_out;
    float* wsb = (float*)d_ws;   // 16 MiB ping buffer

    // level 15: leaf embed -> buf(15) = ws (15 odd)
    grnn_leaf_kernel<<<(N_NODES * H) / BLOCK, BLOCK, 0, stream>>>(contents, Wu, bu, wsb);

    // levels 14..0: buf(k) = (k even) ? out : ws; reads buf(k+1) (opposite parity)
    for (int k = 14; k >= 0; --k) {
        const float* hin  = (((k + 1) & 1) == 0) ? out : wsb;
        float*       hout = ((k & 1) == 0) ? out : wsb;
        grnn_step_kernel<<<N_NODES / NT, BLOCK, 0, stream>>>(
            contents + (size_t)k * N_NODES * FEAT,
            children + (size_t)k * N_NODES * 2,
            hin, Wu, bu, Wr, br, Wh, bh, Wz, bz, hout);
    }
}

// Round 6
// 1294.894 us; speedup vs baseline: 36.2254x; 36.2254x over previous
//
#include <hip/hip_runtime.h>
#include <math.h>

// GRNNTransformGated — round 6 == round 3 resubmit (3x GPU timeout, no data).
// Split-bf16 MFMA (hi/lo x3) fused step kernel.
//
// Per level (14..0), per block: 32 nodes. Pipeline:
//   gather h_L,h_R + leaf-embed u_k -> hhu (bf16 hi/lo, swizzled LDS "zb")
//   GEMM1: r = sigmoid(hhu@Wr.T+br); rh = r*hhu        (rh -> LDS "ubuf")
//   GEMM2: h_H = relu(rh@Wh.T+bh)                      (h_H -> LDS "za", aliases ubuf head)
//   GEMM3: z = [h_H|hhu]@Wz.T+bz; per-gate softmax over 64 j (in-wave shfl)
//   combine: h_new = sum_g softmax_g * comp_g          (phased LDS adds, no atomics)
// Weights pre-split to bf16 hi/lo in exact B-fragment order (coalesced 1KB wave
// loads, L2-resident) by grnn_prep once per launch into d_ws + 16MiB.
// fp32 accuracy ~2^-16 via acc = mfma(alo,bhi, mfma(ahi,blo, mfma(ahi,bhi,acc))).
//
// ws layout: [0,16MiB) h ping buffer ; [16MiB, +448KiB) split weights.
// Fallback to the round-1 fp32 kernel if ws_size is too small.

#define N_NODES 65536
#define FEAT 7
#define H 64
#define MT 32            // nodes per block (2 m-tiles of 16)
#define BLK 256          // 4 waves

typedef __attribute__((ext_vector_type(8))) short bf16x8;
typedef __attribute__((ext_vector_type(4))) short short4v;
typedef __attribute__((ext_vector_type(4))) float f32x4;

__device__ __forceinline__ void split_bf16(float x, short& hi, short& lo) {
    unsigned u = __float_as_uint(x);
    unsigned r = (u + 0x7fffu + ((u >> 16) & 1u)) >> 16;   // RNE to bf16
    hi = (short)r;
    float res = x - __uint_as_float(r << 16);
    unsigned u2 = __float_as_uint(res);
    unsigned r2 = (u2 + 0x7fffu + ((u2 >> 16) & 1u)) >> 16;
    lo = (short)r2;
}
__device__ __forceinline__ float bf2f(short h) {
    return __uint_as_float(((unsigned)(unsigned short)h) << 16);
}
// XOR-swizzled LDS index: 8-elem (16B) chunks, chunk ^= row&7 (T2-style, frag-sized)
__device__ __forceinline__ int zbidx(int row, int col) {   // 192-wide rows
    return row * 192 + ((((col >> 3) ^ (row & 7)) << 3) | (col & 7));
}
__device__ __forceinline__ int zaidx(int row, int col) {   // 64-wide rows
    return row * 64 + ((((col >> 3) ^ (row & 7)) << 3) | (col & 7));
}

#define MFMA3(acc, ah, al, bh8, bl8)                                              \
    acc = __builtin_amdgcn_mfma_f32_16x16x32_bf16(al, bh8, acc, 0, 0, 0);         \
    acc = __builtin_amdgcn_mfma_f32_16x16x32_bf16(ah, bl8, acc, 0, 0, 0);         \
    acc = __builtin_amdgcn_mfma_f32_16x16x32_bf16(ah, bh8, acc, 0, 0, 0);

// ---------------- weight prep: fp32 -> pre-arranged bf16 hi/lo fragments -------
// layout per (nt,s) pair: 1024 shorts = [hi: 64 lanes x 8][lo: 64 lanes x 8]
// lane l holds W[nt*16 + (l&15)][s*32 + (l>>4)*8 + e], e=0..7
__global__ __launch_bounds__(256) void grnn_prep(
    const float* __restrict__ Wr, const float* __restrict__ Wh,
    const float* __restrict__ Wz, short* __restrict__ wsp)
{
    int job = blockIdx.x * 4 + (threadIdx.x >> 6);   // 224 jobs total
    int lane = threadIdx.x & 63;
    const float* src; int K, t, s; short* dst;
    short* ws_wh = wsp + 72 * 1024;
    short* ws_wz = wsp + 96 * 1024;
    if (job < 72)       { t = job / 6;            s = job % 6;        K = 192; src = Wr; dst = wsp   + job * 1024; }
    else if (job < 96)  { int j = job - 72; t = j / 6; s = j % 6;     K = 192; src = Wh; dst = ws_wh + j * 1024; }
    else                { int j = job - 96; t = j / 8; s = j % 8;     K = 256; src = Wz; dst = ws_wz + j * 1024; }
    int i  = t * 16 + (lane & 15);
    int k0 = s * 32 + (lane >> 4) * 8;
    const float* p = src + (size_t)i * K + k0;
    bf16x8 hi, lo;
#pragma unroll
    for (int e = 0; e < 8; ++e) { short h, l; split_bf16(p[e], h, l); hi[e] = h; lo[e] = l; }
    *(bf16x8*)(dst + lane * 8) = hi;
    *(bf16x8*)(dst + 512 + lane * 8) = lo;
}

// ---------------- leaf embed (level 15) ---------------------------------------
__global__ __launch_bounds__(BLK) void grnn_leaf_kernel(
    const float* __restrict__ contents, const float* __restrict__ Wu,
    const float* __restrict__ bu, float* __restrict__ h_out)
{
    int t = blockIdx.x * BLK + threadIdx.x;
    int node = t >> 6;
    int j = t & 63;
    const float* c = contents + (size_t)15 * N_NODES * FEAT + (size_t)node * FEAT;
    float acc = bu[j];
#pragma unroll
    for (int f = 0; f < FEAT; ++f) acc += c[f] * Wu[j * FEAT + f];
    h_out[t] = fmaxf(acc, 0.f);
}

// ---------------- fused MFMA step kernel --------------------------------------
__global__ __launch_bounds__(BLK) void grnn_step_mfma(
    const float* __restrict__ contents_k, const int* __restrict__ children_k,
    const float* __restrict__ h_in,
    const float* __restrict__ Wu, const float* __restrict__ bu,
    const float* __restrict__ br, const float* __restrict__ bh,
    const float* __restrict__ bz,
    const short* __restrict__ wsp, float* __restrict__ h_out)
{
    __shared__ __align__(16) short zb_hi[MT * 192];     // hhu = [h_L|h_R|u_k] hi
    __shared__ __align__(16) short zb_lo[MT * 192];     // hhu lo
    __shared__ __align__(16) short ubuf[2][MT * 192];   // rh hi/lo; head reused as h_H (za)
    __shared__ __align__(16) float hacc[MT * 68];       // combine accumulator

    const int tid = threadIdx.x;
    const int node0 = blockIdx.x * MT;
    const int wv = tid >> 6, lane = tid & 63, lr = lane & 15, lh = lane >> 4;
    const short* wr_s = wsp;
    const short* wh_s = wsp + 72 * 1024;
    const short* wz_s = wsp + 96 * 1024;
    const f32x4 z4 = {0.f, 0.f, 0.f, 0.f};

    // ---- gather h_L / h_R: 64 child rows x 64 floats, 4 threads per row ------
    {
        int row = tid >> 2, q = tid & 3;            // row 0..63
        int nd = row >> 1, side = row & 1;
        int child = children_k[(size_t)(node0 + nd) * 2 + side];
        const float4* src = (const float4*)(h_in + (size_t)child * H + q * 16);
#pragma unroll
        for (int f = 0; f < 4; ++f) {
            float4 v = src[f];
            float vv[4] = {v.x, v.y, v.z, v.w};
            int col0 = side * 64 + q * 16 + f * 4;
            int idx = zbidx(nd, col0);
            short4v h4, l4;
#pragma unroll
            for (int e = 0; e < 4; ++e) {
                short h, l; split_bf16(vv[e], h, l);
                h4[e] = h; l4[e] = l;
            }
            *(short4v*)&zb_hi[idx] = h4;
            *(short4v*)&zb_lo[idx] = l4;
        }
    }
    // ---- u_k = relu(contents @ Wu.T + bu) -> zb cols 128..191 ----------------
    {
        int nd = tid >> 3, j0 = (tid & 7) * 8;
        float c[FEAT];
#pragma unroll
        for (int f = 0; f < FEAT; ++f) c[f] = contents_k[(size_t)(node0 + nd) * FEAT + f];
        bf16x8 hv, lv;
#pragma unroll
        for (int jj = 0; jj < 8; ++jj) {
            int j = j0 + jj;
            float a = bu[j];
#pragma unroll
            for (int f = 0; f < FEAT; ++f) a += c[f] * Wu[j * FEAT + f];
            a = fmaxf(a, 0.f);
            short h, l; split_bf16(a, h, l); hv[jj] = h; lv[jj] = l;
        }
        int idx = zbidx(nd, 128 + j0);
        *(bf16x8*)&zb_hi[idx] = hv;
        *(bf16x8*)&zb_lo[idx] = lv;
    }
    __syncthreads();

    // ---- GEMM1: r-logits = hhu @ Wr.T ; wave wv owns n-tiles {3wv..3wv+2} ----
    f32x4 acc1[2][3];
#pragma unroll
    for (int mi = 0; mi < 2; ++mi)
#pragma unroll
        for (int ni = 0; ni < 3; ++ni) acc1[mi][ni] = z4;
    for (int s = 0; s < 6; ++s) {
        bf16x8 ah[2], al[2];
#pragma unroll
        for (int mi = 0; mi < 2; ++mi) {
            int idx = zbidx(mi * 16 + lr, s * 32 + lh * 8);
            ah[mi] = *(const bf16x8*)&zb_hi[idx];
            al[mi] = *(const bf16x8*)&zb_lo[idx];
        }
#pragma unroll
        for (int ni = 0; ni < 3; ++ni) {
            const short* bp = wr_s + ((3 * wv + ni) * 6 + s) * 1024;
            bf16x8 bh8 = *(const bf16x8*)(bp + lane * 8);
            bf16x8 bl8 = *(const bf16x8*)(bp + 512 + lane * 8);
#pragma unroll
            for (int mi = 0; mi < 2; ++mi) { MFMA3(acc1[mi][ni], ah[mi], al[mi], bh8, bl8); }
        }
    }
    // epilogue1: sigmoid gate, rh = r*hhu -> ubuf (swizzled)
#pragma unroll
    for (int ni = 0; ni < 3; ++ni) {
        int i = (3 * wv + ni) * 16 + lr;
        float brv = br[i];
#pragma unroll
        for (int mi = 0; mi < 2; ++mi) {
#pragma unroll
            for (int r = 0; r < 4; ++r) {
                int nd = mi * 16 + lh * 4 + r;
                float v = acc1[mi][ni][r] + brv;
                float sg = 1.f / (1.f + __expf(-v));
                int xi = zbidx(nd, i);
                float x = bf2f(zb_hi[xi]) + bf2f(zb_lo[xi]);
                short h, l; split_bf16(sg * x, h, l);
                ubuf[0][xi] = h;    // rh shares zb's index formula (192-wide)
                ubuf[1][xi] = l;
            }
        }
    }
    __syncthreads();

    // ---- GEMM2: h_H = relu(rh @ Wh.T + bh) ; wave wv owns n-tile wv ----------
    f32x4 acc2[2] = {z4, z4};
    for (int s = 0; s < 6; ++s) {
        bf16x8 ah[2], al[2];
#pragma unroll
        for (int mi = 0; mi < 2; ++mi) {
            int idx = zbidx(mi * 16 + lr, s * 32 + lh * 8);
            ah[mi] = *(const bf16x8*)&ubuf[0][idx];
            al[mi] = *(const bf16x8*)&ubuf[1][idx];
        }
        const short* bp = wh_s + (wv * 6 + s) * 1024;
        bf16x8 bh8 = *(const bf16x8*)(bp + lane * 8);
        bf16x8 bl8 = *(const bf16x8*)(bp + 512 + lane * 8);
#pragma unroll
        for (int mi = 0; mi < 2; ++mi) { MFMA3(acc2[mi], ah[mi], al[mi], bh8, bl8); }
    }
    __syncthreads();     // all rh reads done before za overwrites ubuf head
    {
        int j = wv * 16 + lr;
        float bhv = bh[j];
#pragma unroll
        for (int mi = 0; mi < 2; ++mi) {
#pragma unroll
            for (int r = 0; r < 4; ++r) {
                int nd = mi * 16 + lh * 4 + r;
                float v = fmaxf(acc2[mi][r] + bhv, 0.f);
                short h, l; split_bf16(v, h, l);
                int idx = zaidx(nd, j);
                ubuf[0][idx] = h;   // za_hi
                ubuf[1][idx] = l;   // za_lo
            }
        }
    }
    __syncthreads();

    // ---- GEMM3: z = [h_H|hhu] @ Wz.T ; wave wv = gate, n-tiles {4wv..4wv+3} --
    f32x4 acc3[2][4];
#pragma unroll
    for (int mi = 0; mi < 2; ++mi)
#pragma unroll
        for (int jh = 0; jh < 4; ++jh) acc3[mi][jh] = z4;
    for (int s = 0; s < 8; ++s) {
        bf16x8 ah[2], al[2];
#pragma unroll
        for (int mi = 0; mi < 2; ++mi) {
            int row = mi * 16 + lr;
            if (s < 2) {
                int idx = zaidx(row, s * 32 + lh * 8);
                ah[mi] = *(const bf16x8*)&ubuf[0][idx];
                al[mi] = *(const bf16x8*)&ubuf[1][idx];
            } else {
                int idx = zbidx(row, s * 32 + lh * 8 - 64);
                ah[mi] = *(const bf16x8*)&zb_hi[idx];
                al[mi] = *(const bf16x8*)&zb_lo[idx];
            }
        }
#pragma unroll
        for (int jh = 0; jh < 4; ++jh) {
            const short* bp = wz_s + ((wv * 4 + jh) * 8 + s) * 1024;
            bf16x8 bh8 = *(const bf16x8*)(bp + lane * 8);
            bf16x8 bl8 = *(const bf16x8*)(bp + 512 + lane * 8);
#pragma unroll
            for (int mi = 0; mi < 2; ++mi) { MFMA3(acc3[mi][jh], ah[mi], al[mi], bh8, bl8); }
        }
    }
    // ---- epilogue3: per-gate softmax over 64 j (in-wave) + gated combine -----
    float bzv[4];
#pragma unroll
    for (int jh = 0; jh < 4; ++jh) bzv[jh] = bz[wv * 64 + jh * 16 + lr];
    float contrib[2][4][4];
#pragma unroll
    for (int mi = 0; mi < 2; ++mi) {
#pragma unroll
        for (int r = 0; r < 4; ++r) {
            float v0 = acc3[mi][0][r] + bzv[0];
            float v1 = acc3[mi][1][r] + bzv[1];
            float v2 = acc3[mi][2][r] + bzv[2];
            float v3 = acc3[mi][3][r] + bzv[3];
            float mx = fmaxf(fmaxf(v0, v1), fmaxf(v2, v3));
            mx = fmaxf(mx, __shfl_xor(mx, 1));
            mx = fmaxf(mx, __shfl_xor(mx, 2));
            mx = fmaxf(mx, __shfl_xor(mx, 4));
            mx = fmaxf(mx, __shfl_xor(mx, 8));
            float e0 = __expf(v0 - mx), e1 = __expf(v1 - mx);
            float e2 = __expf(v2 - mx), e3 = __expf(v3 - mx);
            float sm = e0 + e1 + e2 + e3;
            sm += __shfl_xor(sm, 1);
            sm += __shfl_xor(sm, 2);
            sm += __shfl_xor(sm, 4);
            sm += __shfl_xor(sm, 8);
            float inv = 1.f / sm;
            int nd = mi * 16 + lh * 4 + r;
            float e[4] = {e0, e1, e2, e3};
#pragma unroll
            for (int jh = 0; jh < 4; ++jh) {
                int n = wv * 64 + jh * 16 + lr;
                float comp;
                if (wv == 0) {                     // wave-uniform branch
                    int idx = zaidx(nd, n);
                    comp = bf2f(ubuf[0][idx]) + bf2f(ubuf[1][idx]);
                } else {
                    int idx = zbidx(nd, n - 64);
                    comp = bf2f(zb_hi[idx]) + bf2f(zb_lo[idx]);
                }
                contrib[mi][jh][r] = e[jh] * inv * comp;
            }
        }
    }
    // phased deterministic accumulate (wave p = gate p), no atomics
    for (int p = 0; p < 4; ++p) {
        if (wv == p) {
#pragma unroll
            for (int mi = 0; mi < 2; ++mi)
#pragma unroll
                for (int r = 0; r < 4; ++r) {
                    int nd = mi * 16 + lh * 4 + r;
#pragma unroll
                    for (int jh = 0; jh < 4; ++jh) {
                        int hidx = nd * 68 + jh * 16 + lr;
                        if (p == 0) hacc[hidx] = contrib[mi][jh][r];
                        else        hacc[hidx] += contrib[mi][jh][r];
                    }
                }
        }
        __syncthreads();
    }
    // ---- write out -----------------------------------------------------------
    for (int i = tid; i < MT * H; i += BLK) {
        int nd = i >> 6, j = i & 63;
        h_out[(size_t)(node0 + nd) * H + j] = hacc[nd * 68 + j];
    }
}

// ---------------- round-1 fp32 fallback (used only if ws_size too small) ------
#define HP 196
#define HHP 68
#define ZP 260
#define NT1 16
__global__ __launch_bounds__(BLK) void grnn_step_v1(
    const float* __restrict__ contents_k, const int* __restrict__ children_k,
    const float* __restrict__ h_in,
    const float* __restrict__ Wu, const float* __restrict__ bu,
    const float* __restrict__ Wr, const float* __restrict__ br,
    const float* __restrict__ Wh, const float* __restrict__ bh,
    const float* __restrict__ Wz, const float* __restrict__ bz,
    float* __restrict__ h_out)
{
    __shared__ __align__(16) float hhu[NT1][HP];
    __shared__ __align__(16) float rh[NT1][HP];
    __shared__ __align__(16) float hH[NT1][HHP];
    __shared__ __align__(16) float zt[NT1][ZP];
    __shared__ float rden[NT1][4];
    const int tid = threadIdx.x;
    const int node0 = blockIdx.x * NT1;
    const int n = tid >> 4, c16 = tid & 15;
    {
        const float* cptr = contents_k + (size_t)(node0 + n) * FEAT;
        float cf[FEAT];
#pragma unroll
        for (int f = 0; f < FEAT; ++f) cf[f] = cptr[f];
#pragma unroll
        for (int jj = 0; jj < 4; ++jj) {
            int j = c16 + 16 * jj;
            float acc = bu[j];
#pragma unroll
            for (int f = 0; f < FEAT; ++f) acc += cf[f] * Wu[j * FEAT + f];
            hhu[n][128 + j] = fmaxf(acc, 0.f);
        }
#pragma unroll
        for (int it = 0; it < 8; ++it) {
            int t = tid + it * BLK;
            int nn = t >> 7, side = (t >> 6) & 1, j = t & 63;
            int child = children_k[(size_t)(node0 + nn) * 2 + side];
            hhu[nn][side * 64 + j] = h_in[(size_t)child * H + j];
        }
    }
    __syncthreads();
    {
        float acc[12];
#pragma unroll
        for (int ii = 0; ii < 12; ++ii) acc[ii] = br[c16 + 16 * ii];
        for (int k = 0; k < 192; k += 4) {
            float4 hv = *(const float4*)&hhu[n][k];
#pragma unroll
            for (int ii = 0; ii < 12; ++ii) {
                float4 w = *(const float4*)&Wr[(size_t)(c16 + 16 * ii) * 192 + k];
                acc[ii] += hv.x * w.x + hv.y * w.y + hv.z * w.z + hv.w * w.w;
            }
        }
#pragma unroll
        for (int ii = 0; ii < 12; ++ii) {
            int i = c16 + 16 * ii;
            rh[n][i] = (1.f / (1.f + __expf(-acc[ii]))) * hhu[n][i];
        }
    }
    __syncthreads();
    {
        float acc[4];
#pragma unroll
        for (int ii = 0; ii < 4; ++ii) acc[ii] = bh[c16 + 16 * ii];
        for (int k = 0; k < 192; k += 4) {
            float4 hv = *(const float4*)&rh[n][k];
#pragma unroll
            for (int ii = 0; ii < 4; ++ii) {
                float4 w = *(const float4*)&Wh[(size_t)(c16 + 16 * ii) * 192 + k];
                acc[ii] += hv.x * w.x + hv.y * w.y + hv.z * w.z + hv.w * w.w;
            }
        }
#pragma unroll
        for (int ii = 0; ii < 4; ++ii) hH[n][c16 + 16 * ii] = fmaxf(acc[ii], 0.f);
    }
    __syncthreads();
    {
        float acc[16];
#pragma unroll
        for (int ii = 0; ii < 16; ++ii) acc[ii] = bz[c16 + 16 * ii];
        for (int k = 0; k < 64; k += 4) {
            float4 hv = *(const float4*)&hH[n][k];
#pragma unroll
            for (int ii = 0; ii < 16; ++ii) {
                float4 w = *(const float4*)&Wz[(size_t)(c16 + 16 * ii) * 256 + k];
                acc[ii] += hv.x * w.x + hv.y * w.y + hv.z * w.z + hv.w * w.w;
            }
        }
        for (int k = 0; k < 192; k += 4) {
            float4 hv = *(const float4*)&hhu[n][k];
#pragma unroll
            for (int ii = 0; ii < 16; ++ii) {
                float4 w = *(const float4*)&Wz[(size_t)(c16 + 16 * ii) * 256 + 64 + k];
                acc[ii] += hv.x * w.x + hv.y * w.y + hv.z * w.z + hv.w * w.w;
            }
        }
#pragma unroll
        for (int ii = 0; ii < 16; ++ii) zt[n][c16 + 16 * ii] = acc[ii];
    }
    __syncthreads();
    {
        int sn = tid >> 4, g = (tid >> 2) & 3, q = tid & 3;
        float m = -INFINITY;
#pragma unroll
        for (int jj = 0; jj < 16; ++jj) m = fmaxf(m, zt[sn][g * 64 + q * 16 + jj]);
        m = fmaxf(m, __shfl_xor(m, 1));
        m = fmaxf(m, __shfl_xor(m, 2));
        float s = 0.f;
#pragma unroll
        for (int jj = 0; jj < 16; ++jj) {
            int idx = g * 64 + q * 16 + jj;
            float e = __expf(zt[sn][idx] - m);
            zt[sn][idx] = e;
            s += e;
        }
        s += __shfl_xor(s, 1);
        s += __shfl_xor(s, 2);
        if (q == 0) rden[sn][g] = 1.f / s;
    }
    __syncthreads();
    {
        size_t node = node0 + n;
#pragma unroll
        for (int jj = 0; jj < 4; ++jj) {
            int j = c16 + 16 * jj;
            float v = zt[n][j] * rden[n][0] * hH[n][j]
                    + zt[n][64 + j] * rden[n][1] * hhu[n][j]
                    + zt[n][128 + j] * rden[n][2] * hhu[n][64 + j]
                    + zt[n][192 + j] * rden[n][3] * hhu[n][128 + j];
            h_out[node * H + j] = v;
        }
    }
}

extern "C" void kernel_launch(void* const* d_in, const int* in_sizes, int n_in,
                              void* d_out, int out_size, void* d_ws, size_t ws_size,
                              hipStream_t stream) {
    const float* contents = (const float*)d_in[0];
    const int*   children = (const int*)d_in[1];
    const float* Wu = (const float*)d_in[2];
    const float* bu = (const float*)d_in[3];
    const float* Wr = (const float*)d_in[4];
    const float* br = (const float*)d_in[5];
    const float* Wh = (const float*)d_in[6];
    const float* bh = (const float*)d_in[7];
    const float* Wz = (const float*)d_in[8];
    const float* bz = (const float*)d_in[9];
    float* out = (float*)d_out;
    float* h_ws = (float*)d_ws;                      // 16 MiB ping buffer
    const size_t H_BYTES = (size_t)N_NODES * H * 4;  // 16,777,216
    const size_t W_BYTES = (72 + 24 + 128) * 2048;   // 458,752
    // level 15 (odd parity -> ws)
    grnn_leaf_kernel<<<(N_NODES * H) / BLK, BLK, 0, stream>>>(contents, Wu, bu, h_ws);
    if (ws_size >= H_BYTES + W_BYTES) {
        short* wsp = (short*)((char*)d_ws + H_BYTES);
        grnn_prep<<<56, 256, 0, stream>>>(Wr, Wh, Wz, wsp);
        for (int k = 14; k >= 0; --k) {
            const float* hin = (((k + 1) & 1) == 0) ? out : h_ws;
            float* hout = ((k & 1) == 0) ? out : h_ws;
            grnn_step_mfma<<<N_NODES / MT, BLK, 0, stream>>>(
                contents + (size_t)k * N_NODES * FEAT,
                children + (size_t)k * N_NODES * 2,
                hin, Wu, bu, br, bh, bz, wsp, hout);
        }
    } else {
        for (int k = 14; k >= 0; --k) {
            const float* hin = (((k + 1) & 1) == 0) ? out : h_ws;
            float* hout = ((k & 1) == 0) ? out : h_ws;
            grnn_step_v1<<<N_NODES / NT1, BLK, 0, stream>>>(
                contents + (size_t)k * N_NODES * FEAT,
                children + (size_t)k * N_NODES * 2,
                hin, Wu, bu, Wr, br, Wh, bh, Wz, bz, hout);
        }
    }
}